// Round 4
// baseline (286.603 us; speedup 1.0000x reference)
//
#include <hip/hip_runtime.h>
#include <cmath>

// B=4, S=4096, D_IN=1024, D_K=D_V=64
constexpr int B_  = 4;
constexpr int S_  = 4096;
constexpr int DIN = 1024;
constexpr int DH  = 64;

typedef short bf16x8 __attribute__((ext_vector_type(8)));
typedef float f32x4  __attribute__((ext_vector_type(4)));

#define GPTR(p) (const __attribute__((address_space(1))) unsigned int*)(p)
#define LPTR(p) (__attribute__((address_space(3))) unsigned int*)(p)

// fp32 -> bf16 RNE, raw bits
__device__ __forceinline__ ushort f2bf(float x) {
    unsigned int u = __float_as_uint(x);
    return (ushort)((u + 0x7FFFu + ((u >> 16) & 1u)) >> 16);
}

__device__ __forceinline__ bf16x8 cvt8(float4 a, float4 b) {
    union { bf16x8 v; ushort u[8]; } r;
    r.u[0] = f2bf(a.x); r.u[1] = f2bf(a.y); r.u[2] = f2bf(a.z); r.u[3] = f2bf(a.w);
    r.u[4] = f2bf(b.x); r.u[5] = f2bf(b.y); r.u[6] = f2bf(b.z); r.u[7] = f2bf(b.w);
    return r.v;
}

// softmax scale 1/8 with log2(e) folded in (softmax via exp2)
#define QSCALE 0.18033688011112042f

// ---------------------------------------------------------------------------
// setup_w: W[1024][64] fp32 -> bf16 W^T fragment image (unswizzled):
// Wt_g[y][win(16)][n(64)][p(8)] : 8 bf16 = k-elements win*64+p*8 .. +7 of col n.
// proj reads B-fragments straight from this image (L2-resident, 128KB/y).
// ---------------------------------------------------------------------------
__global__ __launch_bounds__(256) void setup_w(
    const float* __restrict__ Wq, const float* __restrict__ Wk,
    const float* __restrict__ Wv, ushort* __restrict__ Wt_g)
{
    const int y = blockIdx.y;
    const float* W = (y == 0) ? Wq : (y == 1) ? Wk : Wv;
    const int g   = blockIdx.x * 256 + threadIdx.x;   // 0..8191
    const int p   = g & 7;
    const int n   = (g >> 3) & 63;
    const int win = g >> 9;
    const int k0  = win * 64 + p * 8;
    union { uint4 q; ushort u[8]; } r;
    #pragma unroll
    for (int i = 0; i < 8; ++i) r.u[i] = f2bf(W[(size_t)(k0 + i) * DH + n]);
    *(uint4*)(Wt_g + ((size_t)y << 16) + (size_t)(((win * 64 + n) * 8 + p) * 8)) = r.q;
}

// ---------------------------------------------------------------------------
// Projection: out[M,64] = bf16(X @ W + b). grid (256 row-tiles, 3), block 256.
// NO LDS, NO barriers in the main loop: A-frags direct from global fp32
// (inline cvt, pipelined one window ahead), B-frags direct from the bf16
// W^T image (L1/L2 hits; all 12 waves/CU share the same 8KB window).
// Q pre-scaled by 0.125*log2e. V written transposed Vt[b][d][s] via a
// dedicated 9KB LDS transpose in the epilogue.
// ---------------------------------------------------------------------------
__global__ __launch_bounds__(256, 3) void proj_kernel(
    const float* __restrict__ Xq, const float* __restrict__ Xk, const float* __restrict__ Xv,
    const float* __restrict__ bq, const float* __restrict__ bk, const float* __restrict__ bv,
    const ushort* __restrict__ Wt_g,
    ushort* __restrict__ Qb, ushort* __restrict__ Kb, ushort* __restrict__ Vt)
{
    const int y = blockIdx.y;
    const float *X, *bias;
    if (y == 0)      { X = Xq; bias = bq; }
    else if (y == 1) { X = Xk; bias = bk; }
    else             { X = Xv; bias = bv; }

    __shared__ ushort Vx[64 * 72];   // epilogue transpose only (y==2)

    const int tid  = threadIdx.x;
    const int w    = tid >> 6;
    const int lane = tid & 63;
    const int m    = lane & 15;
    const int quad = lane >> 4;
    const int row0 = blockIdx.x * 64;

    const size_t  xrow  = (size_t)(row0 + w * 16 + m) * DIN;
    const ushort* wbase = Wt_g + ((size_t)y << 16);

    float bias_v[4];
    #pragma unroll
    for (int nt = 0; nt < 4; ++nt) bias_v[nt] = bias[nt * 16 + m];

    f32x4 acc[4] = {};

    // prefetch X window 0
    float4 cur[4], nxt[4];
    {
        const float* px = X + xrow + quad * 8;
        cur[0] = *(const float4*)(px);      cur[1] = *(const float4*)(px + 4);
        cur[2] = *(const float4*)(px + 32); cur[3] = *(const float4*)(px + 36);
    }

    for (int it = 0; it < 16; ++it) {
        // B-frags for this window, straight from global (L1/L2)
        bf16x8 wf[2][4];
        #pragma unroll
        for (int ks = 0; ks < 2; ++ks)
            #pragma unroll
            for (int nt = 0; nt < 4; ++nt)
                wf[ks][nt] = *(const bf16x8*)(wbase
                    + (size_t)(((it * 64 + nt * 16 + m) * 8 + ks * 4 + quad) * 8));
        // prefetch X window it+1
        if (it < 15) {
            const float* px = X + xrow + (it + 1) * 64 + quad * 8;
            nxt[0] = *(const float4*)(px);      nxt[1] = *(const float4*)(px + 4);
            nxt[2] = *(const float4*)(px + 32); nxt[3] = *(const float4*)(px + 36);
        }
        #pragma unroll
        for (int ks = 0; ks < 2; ++ks) {
            const bf16x8 a = cvt8(cur[ks * 2], cur[ks * 2 + 1]);
            #pragma unroll
            for (int nt = 0; nt < 4; ++nt)
                acc[nt] = __builtin_amdgcn_mfma_f32_16x16x32_bf16(a, wf[ks][nt], acc[nt], 0, 0, 0);
        }
        #pragma unroll
        for (int i = 0; i < 4; ++i) cur[i] = nxt[i];
    }

    if (y < 2) {
        ushort* Out = (y == 0) ? Qb : Kb;
        const float sc = (y == 0) ? QSCALE : 1.0f;
        #pragma unroll
        for (int nt = 0; nt < 4; ++nt)
            #pragma unroll
            for (int j = 0; j < 4; ++j) {
                const int row = row0 + w * 16 + quad * 4 + j;
                Out[(size_t)row * DH + nt * 16 + m] = f2bf((acc[nt][j] + bias_v[nt]) * sc);
            }
    } else {
        // V: transpose via LDS, chunk-XOR swizzled, then 16B stores
        #pragma unroll
        for (int nt = 0; nt < 4; ++nt)
            #pragma unroll
            for (int j = 0; j < 4; ++j) {
                const int d = nt * 16 + m;
                const int s = w * 16 + quad * 4 + j;
                Vx[d * 72 + (((s >> 3) ^ (d & 7)) * 8) + (s & 7)] = f2bf(acc[nt][j] + bias_v[nt]);
            }
        __syncthreads();
        const int batch = row0 >> 12;
        const int s0    = row0 & 4095;
        for (int i = tid; i < 512; i += 256) {
            const int d = i >> 3, c = i & 7;
            const uint4 v = *(const uint4*)&Vx[d * 72 + ((c ^ (d & 7)) * 8)];
            *(uint4*)(Vt + ((size_t)batch * 64 + d) * S_ + s0 + c * 8) = v;
        }
    }
}

// ---------------------------------------------------------------------------
// Flash attention, bf16 MFMA, no online max; softmax via exp2 (Q carries
// 0.125*log2e). grid (64 q-tiles, 4 j-chunks, 4 batches) = 1024 blocks.
// SINGLE-barrier double-buffered K/V staging: the barrier's implicit
// vmcnt(0) drains DMA issued one full iteration earlier -> near-free.
// K/V DMA'd with XOR swizzle folded into SOURCE addresses. P round-trips
// through a per-wave LDS stripe (same-wave RAW, no barrier).
// ---------------------------------------------------------------------------
__global__ __launch_bounds__(256, 3) void attn_kernel(
    const ushort* __restrict__ Qb, const ushort* __restrict__ Kb,
    const ushort* __restrict__ Vt, float* __restrict__ Opart, float* __restrict__ Lpart)
{
    __shared__ ushort Ks[2][4096];   // [j][d], chunk-XOR swizzled
    __shared__ ushort Vs[2][4096];   // [d][j], chunk-XOR swizzled
    __shared__ ushort Pt[64 * 72];   // per-wave stripes, padded

    const int tid  = threadIdx.x;
    const int w    = tid >> 6;
    const int lane = tid & 63;
    const int m    = lane & 15;
    const int quad = lane >> 4;
    const int b    = blockIdx.z, jc = blockIdx.y, qt = blockIdx.x;
    const int q0   = qt * 64;

    bf16x8 qf[2];
    #pragma unroll
    for (int ks = 0; ks < 2; ++ks)
        qf[ks] = *(const bf16x8*)(Qb + (size_t)(b * S_ + q0 + w * 16 + m) * 64
                                     + ks * 32 + quad * 8);

    f32x4 acc_o[4] = {};
    float Lp[4] = {};

    const ushort* kbase = Kb + (size_t)b * S_ * 64;
    const ushort* vbase = Vt + (size_t)b * 64 * S_;

    // DMA slot assignment (per wave): 2 chunks of 64 lanes each for K and V
    const int slot0 = w * 128 + lane;          // +0 / +64
    const int j0 = slot0 >> 3, c0 = slot0 & 7;
    const int j1 = (slot0 + 64) >> 3, c1 = (slot0 + 64) & 7;

    #define ISSUE_DMA(IT, NB)                                                          \
        do {                                                                           \
            const int _jt = jc * 16 + (IT);                                            \
            __builtin_amdgcn_global_load_lds(                                          \
                GPTR(kbase + (size_t)(_jt * 64 + j0) * 64 + ((c0 ^ (j0 & 7)) * 8)),    \
                LPTR(&Ks[NB][(w * 128) * 8]), 16, 0, 0);                               \
            __builtin_amdgcn_global_load_lds(                                          \
                GPTR(kbase + (size_t)(_jt * 64 + j1) * 64 + ((c1 ^ (j1 & 7)) * 8)),    \
                LPTR(&Ks[NB][(w * 128 + 64) * 8]), 16, 0, 0);                          \
            __builtin_amdgcn_global_load_lds(                                          \
                GPTR(vbase + (size_t)j0 * S_ + _jt * 64 + ((c0 ^ (j0 & 7)) * 8)),      \
                LPTR(&Vs[NB][(w * 128) * 8]), 16, 0, 0);                               \
            __builtin_amdgcn_global_load_lds(                                          \
                GPTR(vbase + (size_t)j1 * S_ + _jt * 64 + ((c1 ^ (j1 & 7)) * 8)),      \
                LPTR(&Vs[NB][(w * 128 + 64) * 8]), 16, 0, 0);                          \
        } while (0)

    ISSUE_DMA(0, 0);

    for (int it = 0; it < 16; ++it) {
        __syncthreads();               // drains vmcnt(0): DMA(it) complete (issued 1 iter ago)
        if (it < 15) ISSUE_DMA(it + 1, (it + 1) & 1);
        const int cb = it & 1;

        // S2 = (Q * 0.125*log2e) K^T
        f32x4 acc_s[4] = {};
        #pragma unroll
        for (int ks = 0; ks < 2; ++ks)
            #pragma unroll
            for (int jt4 = 0; jt4 < 4; ++jt4) {
                const int j = jt4 * 16 + m;
                const bf16x8 kf = *(const bf16x8*)&Ks[cb][j * 64 + (((ks * 4 + quad) ^ (j & 7)) * 8)];
                acc_s[jt4] = __builtin_amdgcn_mfma_f32_16x16x32_bf16(
                    qf[ks], kf, acc_s[jt4], 0, 0, 0);
            }

        // P = exp2(S2); L += rowsum; P -> per-wave LDS stripe (bf16)
        #pragma unroll
        for (int jt4 = 0; jt4 < 4; ++jt4)
            #pragma unroll
            for (int r = 0; r < 4; ++r) {
                const float e = exp2f(acc_s[jt4][r]);
                Lp[r] += e;
                Pt[(w * 16 + quad * 4 + r) * 72 + jt4 * 16 + m] = f2bf(e);
            }

        // O += P V (same-wave LDS RAW, ordered by lgkmcnt)
        #pragma unroll
        for (int jc2 = 0; jc2 < 2; ++jc2) {
            const bf16x8 pf = *(const bf16x8*)&Pt[(w * 16 + m) * 72 + jc2 * 32 + quad * 8];
            #pragma unroll
            for (int dt = 0; dt < 4; ++dt) {
                const int d = dt * 16 + m;
                const bf16x8 vf = *(const bf16x8*)&Vs[cb][d * 64 + (((jc2 * 4 + quad) ^ (d & 7)) * 8)];
                acc_o[dt] = __builtin_amdgcn_mfma_f32_16x16x32_bf16(pf, vf, acc_o[dt], 0, 0, 0);
            }
        }
    }
    #undef ISSUE_DMA

    #pragma unroll
    for (int r = 0; r < 4; ++r) {
        float s = Lp[r];
        #pragma unroll
        for (int off = 1; off < 16; off <<= 1)
            s += __shfl_xor(s, off, 64);
        Lp[r] = s;
    }

    const size_t bj = (size_t)(b * 4 + jc);
    float* Ob = Opart + (bj << 18);
    #pragma unroll
    for (int dt = 0; dt < 4; ++dt)
        #pragma unroll
        for (int r = 0; r < 4; ++r) {
            const int row = q0 + w * 16 + quad * 4 + r;
            Ob[(size_t)row * 64 + dt * 16 + m] = acc_o[dt][r];
        }
    if (m == 0) {
        #pragma unroll
        for (int r = 0; r < 4; ++r)
            Lpart[bj * 4096 + q0 + w * 16 + quad * 4 + r] = Lp[r];
    }
}

// ---------------------------------------------------------------------------
// Combine j-chunk partials: out = (sum_jc O) / (sum_jc L)
// ---------------------------------------------------------------------------
__global__ __launch_bounds__(256) void reduce_kernel(
    const float* __restrict__ Opart, const float* __restrict__ Lpart, float* __restrict__ out)
{
    const int g    = blockIdx.x * 256 + threadIdx.x;
    const int base = g << 2;
    const int b    = base >> 18;
    const int rem  = base & 0x3FFFF;
    const int q    = rem >> 6;
    float4 o = make_float4(0.f, 0.f, 0.f, 0.f);
    float  l = 0.f;
    #pragma unroll
    for (int jcc = 0; jcc < 4; ++jcc) {
        const float4 p = *(const float4*)(Opart + (((size_t)(b * 4 + jcc)) << 18) + rem);
        o.x += p.x; o.y += p.y; o.z += p.z; o.w += p.w;
        l += Lpart[(size_t)(b * 4 + jcc) * 4096 + q];
    }
    const float inv = 1.0f / l;
    o.x *= inv; o.y *= inv; o.z *= inv; o.w *= inv;
    *(float4*)(out + base) = o;
}

// ---------------------------------------------------------------------------
extern "C" void kernel_launch(void* const* d_in, const int* in_sizes, int n_in,
                              void* d_out, int out_size, void* d_ws, size_t ws_size,
                              hipStream_t stream)
{
    const float* query = (const float*)d_in[0];
    const float* key_  = (const float*)d_in[1];
    const float* value = (const float*)d_in[2];
    const float* Wq    = (const float*)d_in[3];
    const float* bq    = (const float*)d_in[4];
    const float* Wk    = (const float*)d_in[5];
    const float* bk    = (const float*)d_in[6];
    const float* Wv    = (const float*)d_in[7];
    const float* bv    = (const float*)d_in[8];
    float* out = (float*)d_out;

    // ws: Qb 2MB | Kb 2MB | Vt 2MB | Opart 16MB | Lpart 256KB  (22.25MB)
    // Wt_g (384KB) ALIASES Opart: consumed by proj before attn writes Opart.
    char* ws = (char*)d_ws;
    ushort* Qb    = (ushort*)(ws);
    ushort* Kb    = (ushort*)(ws + (2  << 20));
    ushort* Vt    = (ushort*)(ws + (4  << 20));
    float*  Opart = (float*) (ws + (6  << 20));
    float*  Lpart = (float*) (ws + (22 << 20));
    ushort* Wt_g  = (ushort*)(ws + (6  << 20));

    setup_w<<<dim3(32, 3), 256, 0, stream>>>(Wq, Wk, Wv, Wt_g);
    proj_kernel<<<dim3(256, 3), 256, 0, stream>>>(
        query, key_, value, bq, bk, bv, Wt_g, Qb, Kb, Vt);
    attn_kernel<<<dim3(64, 4, 4), 256, 0, stream>>>(Qb, Kb, Vt, Opart, Lpart);
    reduce_kernel<<<dim3(1024), 256, 0, stream>>>(Opart, Lpart, out);
}

// Round 5
// 284.569 us; speedup vs baseline: 1.0071x; 1.0071x over previous
//
#include <hip/hip_runtime.h>
#include <cmath>

// B=4, S=4096, D_IN=1024, D_K=D_V=64
constexpr int B_  = 4;
constexpr int S_  = 4096;
constexpr int DIN = 1024;
constexpr int DH  = 64;

typedef short bf16x8 __attribute__((ext_vector_type(8)));
typedef float f32x4  __attribute__((ext_vector_type(4)));

#define GPTR(p) (const __attribute__((address_space(1))) unsigned int*)(p)
#define LPTR(p) (__attribute__((address_space(3))) unsigned int*)(p)

// fp32 -> bf16 RNE, raw bits
__device__ __forceinline__ ushort f2bf(float x) {
    unsigned int u = __float_as_uint(x);
    return (ushort)((u + 0x7FFFu + ((u >> 16) & 1u)) >> 16);
}

__device__ __forceinline__ bf16x8 cvt8(float4 a, float4 b) {
    union { bf16x8 v; ushort u[8]; } r;
    r.u[0] = f2bf(a.x); r.u[1] = f2bf(a.y); r.u[2] = f2bf(a.z); r.u[3] = f2bf(a.w);
    r.u[4] = f2bf(b.x); r.u[5] = f2bf(b.y); r.u[6] = f2bf(b.z); r.u[7] = f2bf(b.w);
    return r.v;
}

// softmax scale 1/8 with log2(e) folded in (softmax via exp2)
#define QSCALE 0.18033688011112042f

// ---------------------------------------------------------------------------
// setup_w: W[1024][64] fp32 -> bf16 W^T fragment image (unswizzled):
// Wt_g[y][win(16)][n(64)][p(8)] : 8 bf16 = k-elements win*64+p*8 .. +7 of col n.
// proj reads B-fragments straight from this image (L2-resident, 128KB/y).
// ---------------------------------------------------------------------------
__global__ __launch_bounds__(256) void setup_w(
    const float* __restrict__ Wq, const float* __restrict__ Wk,
    const float* __restrict__ Wv, ushort* __restrict__ Wt_g)
{
    const int y = blockIdx.y;
    const float* W = (y == 0) ? Wq : (y == 1) ? Wk : Wv;
    const int g   = blockIdx.x * 256 + threadIdx.x;   // 0..8191
    const int p   = g & 7;
    const int n   = (g >> 3) & 63;
    const int win = g >> 9;
    const int k0  = win * 64 + p * 8;
    union { uint4 q; ushort u[8]; } r;
    #pragma unroll
    for (int i = 0; i < 8; ++i) r.u[i] = f2bf(W[(size_t)(k0 + i) * DH + n]);
    *(uint4*)(Wt_g + ((size_t)y << 16) + (size_t)(((win * 64 + n) * 8 + p) * 8)) = r.q;
}

// ---------------------------------------------------------------------------
// Projection: out[M,64] = bf16(X @ W + b). grid (256 row-tiles, 3), block 256.
// NO LDS, NO barriers in the main loop. BOTH operands register-pipelined one
// 64-k window ahead: X (fp32, own row per lane, cvt inline) and W (bf16 frag
// image, L1/L2-hit). Loads for window it+1 issue at the top of iteration it;
// MFMAs consume regs loaded a full iteration earlier -> latency covered by
// ~16 MFMA + cvt of 12 waves/CU. Q pre-scaled by 0.125*log2e. V written
// transposed Vt[b][d][s] via a 9KB LDS transpose in the epilogue.
// ---------------------------------------------------------------------------
__global__ __launch_bounds__(256, 3) void proj_kernel(
    const float* __restrict__ Xq, const float* __restrict__ Xk, const float* __restrict__ Xv,
    const float* __restrict__ bq, const float* __restrict__ bk, const float* __restrict__ bv,
    const ushort* __restrict__ Wt_g,
    ushort* __restrict__ Qb, ushort* __restrict__ Kb, ushort* __restrict__ Vt)
{
    const int y = blockIdx.y;
    const float *X, *bias;
    if (y == 0)      { X = Xq; bias = bq; }
    else if (y == 1) { X = Xk; bias = bk; }
    else             { X = Xv; bias = bv; }

    __shared__ ushort Vx[64 * 72];   // epilogue transpose only (y==2)

    const int tid  = threadIdx.x;
    const int w    = tid >> 6;
    const int lane = tid & 63;
    const int m    = lane & 15;
    const int quad = lane >> 4;
    const int row0 = blockIdx.x * 64;

    const size_t  xrow  = (size_t)(row0 + w * 16 + m) * DIN;
    const ushort* wbase = Wt_g + ((size_t)y << 16);

    float bias_v[4];
    #pragma unroll
    for (int nt = 0; nt < 4; ++nt) bias_v[nt] = bias[nt * 16 + m];

    f32x4 acc[4] = {};

    float4 xcur[4], xnxt[4];
    bf16x8 wcur[8], wnxt[8];

    // prologue: window 0 for both operands
    {
        const float* px = X + xrow + quad * 8;
        xcur[0] = *(const float4*)(px);      xcur[1] = *(const float4*)(px + 4);
        xcur[2] = *(const float4*)(px + 32); xcur[3] = *(const float4*)(px + 36);
        #pragma unroll
        for (int ks = 0; ks < 2; ++ks)
            #pragma unroll
            for (int nt = 0; nt < 4; ++nt)
                wcur[ks * 4 + nt] = *(const bf16x8*)(wbase
                    + (size_t)(((nt * 16 + m) * 8 + ks * 4 + quad) * 8));
    }

    for (int it = 0; it < 16; ++it) {
        if (it < 15) {
            const float* px = X + xrow + (it + 1) * 64 + quad * 8;
            xnxt[0] = *(const float4*)(px);      xnxt[1] = *(const float4*)(px + 4);
            xnxt[2] = *(const float4*)(px + 32); xnxt[3] = *(const float4*)(px + 36);
            #pragma unroll
            for (int ks = 0; ks < 2; ++ks)
                #pragma unroll
                for (int nt = 0; nt < 4; ++nt)
                    wnxt[ks * 4 + nt] = *(const bf16x8*)(wbase
                        + (size_t)((((it + 1) * 64 + nt * 16 + m) * 8 + ks * 4 + quad) * 8));
        }
        #pragma unroll
        for (int ks = 0; ks < 2; ++ks) {
            const bf16x8 a = cvt8(xcur[ks * 2], xcur[ks * 2 + 1]);
            #pragma unroll
            for (int nt = 0; nt < 4; ++nt)
                acc[nt] = __builtin_amdgcn_mfma_f32_16x16x32_bf16(
                    a, wcur[ks * 4 + nt], acc[nt], 0, 0, 0);
        }
        #pragma unroll
        for (int i = 0; i < 4; ++i) xcur[i] = xnxt[i];
        #pragma unroll
        for (int i = 0; i < 8; ++i) wcur[i] = wnxt[i];
    }

    if (y < 2) {
        ushort* Out = (y == 0) ? Qb : Kb;
        const float sc = (y == 0) ? QSCALE : 1.0f;
        #pragma unroll
        for (int nt = 0; nt < 4; ++nt)
            #pragma unroll
            for (int j = 0; j < 4; ++j) {
                const int row = row0 + w * 16 + quad * 4 + j;
                Out[(size_t)row * DH + nt * 16 + m] = f2bf((acc[nt][j] + bias_v[nt]) * sc);
            }
    } else {
        // V: transpose via LDS, chunk-XOR swizzled, then 16B stores
        #pragma unroll
        for (int nt = 0; nt < 4; ++nt)
            #pragma unroll
            for (int j = 0; j < 4; ++j) {
                const int d = nt * 16 + m;
                const int s = w * 16 + quad * 4 + j;
                Vx[d * 72 + (((s >> 3) ^ (d & 7)) * 8) + (s & 7)] = f2bf(acc[nt][j] + bias_v[nt]);
            }
        __syncthreads();
        const int batch = row0 >> 12;
        const int s0    = row0 & 4095;
        for (int i = tid; i < 512; i += 256) {
            const int d = i >> 3, c = i & 7;
            const uint4 v = *(const uint4*)&Vx[d * 72 + ((c ^ (d & 7)) * 8)];
            *(uint4*)(Vt + ((size_t)batch * 64 + d) * S_ + s0 + c * 8) = v;
        }
    }
}

// ---------------------------------------------------------------------------
// Flash attention, bf16 MFMA, no online max; softmax via exp2 (Q carries
// 0.125*log2e). grid (64 q-tiles, 4 j-chunks, 4 batches) = 1024 blocks.
// SINGLE-barrier double-buffered K/V staging: the barrier's implicit
// vmcnt(0) drains DMA issued one full iteration earlier -> near-free.
// K/V DMA'd with XOR swizzle folded into SOURCE addresses. P round-trips
// through a per-wave LDS stripe (same-wave RAW, no barrier).
// ---------------------------------------------------------------------------
__global__ __launch_bounds__(256, 3) void attn_kernel(
    const ushort* __restrict__ Qb, const ushort* __restrict__ Kb,
    const ushort* __restrict__ Vt, float* __restrict__ Opart, float* __restrict__ Lpart)
{
    __shared__ ushort Ks[2][4096];   // [j][d], chunk-XOR swizzled
    __shared__ ushort Vs[2][4096];   // [d][j], chunk-XOR swizzled
    __shared__ ushort Pt[64 * 72];   // per-wave stripes, padded

    const int tid  = threadIdx.x;
    const int w    = tid >> 6;
    const int lane = tid & 63;
    const int m    = lane & 15;
    const int quad = lane >> 4;
    const int b    = blockIdx.z, jc = blockIdx.y, qt = blockIdx.x;
    const int q0   = qt * 64;

    bf16x8 qf[2];
    #pragma unroll
    for (int ks = 0; ks < 2; ++ks)
        qf[ks] = *(const bf16x8*)(Qb + (size_t)(b * S_ + q0 + w * 16 + m) * 64
                                     + ks * 32 + quad * 8);

    f32x4 acc_o[4] = {};
    float Lp[4] = {};

    const ushort* kbase = Kb + (size_t)b * S_ * 64;
    const ushort* vbase = Vt + (size_t)b * 64 * S_;

    const int slot0 = w * 128 + lane;
    const int j0 = slot0 >> 3, c0 = slot0 & 7;
    const int j1 = (slot0 + 64) >> 3, c1 = (slot0 + 64) & 7;

    #define ISSUE_DMA(IT, NB)                                                          \
        do {                                                                           \
            const int _jt = jc * 16 + (IT);                                            \
            __builtin_amdgcn_global_load_lds(                                          \
                GPTR(kbase + (size_t)(_jt * 64 + j0) * 64 + ((c0 ^ (j0 & 7)) * 8)),    \
                LPTR(&Ks[NB][(w * 128) * 8]), 16, 0, 0);                               \
            __builtin_amdgcn_global_load_lds(                                          \
                GPTR(kbase + (size_t)(_jt * 64 + j1) * 64 + ((c1 ^ (j1 & 7)) * 8)),    \
                LPTR(&Ks[NB][(w * 128 + 64) * 8]), 16, 0, 0);                          \
            __builtin_amdgcn_global_load_lds(                                          \
                GPTR(vbase + (size_t)j0 * S_ + _jt * 64 + ((c0 ^ (j0 & 7)) * 8)),      \
                LPTR(&Vs[NB][(w * 128) * 8]), 16, 0, 0);                               \
            __builtin_amdgcn_global_load_lds(                                          \
                GPTR(vbase + (size_t)j1 * S_ + _jt * 64 + ((c1 ^ (j1 & 7)) * 8)),      \
                LPTR(&Vs[NB][(w * 128 + 64) * 8]), 16, 0, 0);                          \
        } while (0)

    ISSUE_DMA(0, 0);

    for (int it = 0; it < 16; ++it) {
        __syncthreads();               // drains vmcnt(0): DMA(it) complete (issued 1 iter ago)
        if (it < 15) ISSUE_DMA(it + 1, (it + 1) & 1);
        const int cb = it & 1;

        // S2 = (Q * 0.125*log2e) K^T
        f32x4 acc_s[4] = {};
        #pragma unroll
        for (int ks = 0; ks < 2; ++ks)
            #pragma unroll
            for (int jt4 = 0; jt4 < 4; ++jt4) {
                const int j = jt4 * 16 + m;
                const bf16x8 kf = *(const bf16x8*)&Ks[cb][j * 64 + (((ks * 4 + quad) ^ (j & 7)) * 8)];
                acc_s[jt4] = __builtin_amdgcn_mfma_f32_16x16x32_bf16(
                    qf[ks], kf, acc_s[jt4], 0, 0, 0);
            }

        // P = exp2(S2); L += rowsum; P -> per-wave LDS stripe (bf16)
        #pragma unroll
        for (int jt4 = 0; jt4 < 4; ++jt4)
            #pragma unroll
            for (int r = 0; r < 4; ++r) {
                const float e = exp2f(acc_s[jt4][r]);
                Lp[r] += e;
                Pt[(w * 16 + quad * 4 + r) * 72 + jt4 * 16 + m] = f2bf(e);
            }

        // O += P V (same-wave LDS RAW, ordered by lgkmcnt)
        #pragma unroll
        for (int jc2 = 0; jc2 < 2; ++jc2) {
            const bf16x8 pf = *(const bf16x8*)&Pt[(w * 16 + m) * 72 + jc2 * 32 + quad * 8];
            #pragma unroll
            for (int dt = 0; dt < 4; ++dt) {
                const int d = dt * 16 + m;
                const bf16x8 vf = *(const bf16x8*)&Vs[cb][d * 64 + (((jc2 * 4 + quad) ^ (d & 7)) * 8)];
                acc_o[dt] = __builtin_amdgcn_mfma_f32_16x16x32_bf16(pf, vf, acc_o[dt], 0, 0, 0);
            }
        }
    }
    #undef ISSUE_DMA

    #pragma unroll
    for (int r = 0; r < 4; ++r) {
        float s = Lp[r];
        #pragma unroll
        for (int off = 1; off < 16; off <<= 1)
            s += __shfl_xor(s, off, 64);
        Lp[r] = s;
    }

    const size_t bj = (size_t)(b * 4 + jc);
    float* Ob = Opart + (bj << 18);
    #pragma unroll
    for (int dt = 0; dt < 4; ++dt)
        #pragma unroll
        for (int r = 0; r < 4; ++r) {
            const int row = q0 + w * 16 + quad * 4 + r;
            Ob[(size_t)row * 64 + dt * 16 + m] = acc_o[dt][r];
        }
    if (m == 0) {
        #pragma unroll
        for (int r = 0; r < 4; ++r)
            Lpart[bj * 4096 + q0 + w * 16 + quad * 4 + r] = Lp[r];
    }
}

// ---------------------------------------------------------------------------
// Combine j-chunk partials: out = (sum_jc O) / (sum_jc L)
// ---------------------------------------------------------------------------
__global__ __launch_bounds__(256) void reduce_kernel(
    const float* __restrict__ Opart, const float* __restrict__ Lpart, float* __restrict__ out)
{
    const int g    = blockIdx.x * 256 + threadIdx.x;
    const int base = g << 2;
    const int b    = base >> 18;
    const int rem  = base & 0x3FFFF;
    const int q    = rem >> 6;
    float4 o = make_float4(0.f, 0.f, 0.f, 0.f);
    float  l = 0.f;
    #pragma unroll
    for (int jcc = 0; jcc < 4; ++jcc) {
        const float4 p = *(const float4*)(Opart + (((size_t)(b * 4 + jcc)) << 18) + rem);
        o.x += p.x; o.y += p.y; o.z += p.z; o.w += p.w;
        l += Lpart[(size_t)(b * 4 + jcc) * 4096 + q];
    }
    const float inv = 1.0f / l;
    o.x *= inv; o.y *= inv; o.z *= inv; o.w *= inv;
    *(float4*)(out + base) = o;
}

// ---------------------------------------------------------------------------
extern "C" void kernel_launch(void* const* d_in, const int* in_sizes, int n_in,
                              void* d_out, int out_size, void* d_ws, size_t ws_size,
                              hipStream_t stream)
{
    const float* query = (const float*)d_in[0];
    const float* key_  = (const float*)d_in[1];
    const float* value = (const float*)d_in[2];
    const float* Wq    = (const float*)d_in[3];
    const float* bq    = (const float*)d_in[4];
    const float* Wk    = (const float*)d_in[5];
    const float* bk    = (const float*)d_in[6];
    const float* Wv    = (const float*)d_in[7];
    const float* bv    = (const float*)d_in[8];
    float* out = (float*)d_out;

    // ws: Qb 2MB | Kb 2MB | Vt 2MB | Opart 16MB | Lpart 256KB  (22.25MB)
    // Wt_g (384KB) ALIASES Opart: consumed by proj before attn writes Opart.
    char* ws = (char*)d_ws;
    ushort* Qb    = (ushort*)(ws);
    ushort* Kb    = (ushort*)(ws + (2  << 20));
    ushort* Vt    = (ushort*)(ws + (4  << 20));
    float*  Opart = (float*) (ws + (6  << 20));
    float*  Lpart = (float*) (ws + (22 << 20));
    ushort* Wt_g  = (ushort*)(ws + (6  << 20));

    setup_w<<<dim3(32, 3), 256, 0, stream>>>(Wq, Wk, Wv, Wt_g);
    proj_kernel<<<dim3(256, 3), 256, 0, stream>>>(
        query, key_, value, bq, bk, bv, Wt_g, Qb, Kb, Vt);
    attn_kernel<<<dim3(64, 4, 4), 256, 0, stream>>>(Qb, Kb, Vt, Opart, Lpart);
    reduce_kernel<<<dim3(1024), 256, 0, stream>>>(Opart, Lpart, out);
}

// Round 6
// 273.573 us; speedup vs baseline: 1.0476x; 1.0402x over previous
//
#include <hip/hip_runtime.h>
#include <cmath>

// B=4, S=4096, D_IN=1024, D_K=D_V=64
constexpr int B_  = 4;
constexpr int S_  = 4096;
constexpr int DIN = 1024;
constexpr int DH  = 64;

typedef short bf16x8 __attribute__((ext_vector_type(8)));
typedef float f32x4  __attribute__((ext_vector_type(4)));

#define GPTR(p) (const __attribute__((address_space(1))) unsigned int*)(p)
#define LPTR(p) (__attribute__((address_space(3))) unsigned int*)(p)

// fp32 -> bf16 RNE, raw bits
__device__ __forceinline__ ushort f2bf(float x) {
    unsigned int u = __float_as_uint(x);
    return (ushort)((u + 0x7FFFu + ((u >> 16) & 1u)) >> 16);
}

__device__ __forceinline__ bf16x8 cvt8(float4 a, float4 b) {
    union { bf16x8 v; ushort u[8]; } r;
    r.u[0] = f2bf(a.x); r.u[1] = f2bf(a.y); r.u[2] = f2bf(a.z); r.u[3] = f2bf(a.w);
    r.u[4] = f2bf(b.x); r.u[5] = f2bf(b.y); r.u[6] = f2bf(b.z); r.u[7] = f2bf(b.w);
    return r.v;
}

// softmax scale 1/8 with log2(e) folded in (softmax via exp2)
#define QSCALE 0.18033688011112042f

// X LDS chunk swizzle: 16B chunks, 16 per row; XOR low 3 bits with row&7
__device__ __forceinline__ int xswz(int c, int r) {
    return (c & 8) | ((c & 7) ^ (r & 7));
}

// ---------------------------------------------------------------------------
// setup_w: W[1024][64] fp32 -> bf16 W^T image, FRAGMENT-MAJOR:
//   Wt_g[y][win(16)][frag p(8)][n(64)] of 8 bf16 (k = win*64 + p*8 .. +7).
// Lane m reading frag (win,p,n=nt*16+m) -> 16 consecutive 16B = 256B ✓.
// Coalesced global reads via LDS transpose.
// ---------------------------------------------------------------------------
__global__ __launch_bounds__(256) void setup_w(
    const float* __restrict__ Wq, const float* __restrict__ Wk,
    const float* __restrict__ Wv, ushort* __restrict__ Wt_g)
{
    __shared__ ushort Ws[64 * 72];   // [n][k] bf16, padded
    const int y = blockIdx.y, win = blockIdx.x, tid = threadIdx.x;
    const float* W = (y == 0) ? Wq : (y == 1) ? Wk : Wv;

    for (int i = tid; i < 1024; i += 256) {       // 64 k-rows x 16 n-groups
        const int k = i >> 4, n4 = (i & 15) << 2;
        const float4 f = *(const float4*)(W + (size_t)(win * 64 + k) * DH + n4);
        Ws[(n4 + 0) * 72 + k] = f2bf(f.x);
        Ws[(n4 + 1) * 72 + k] = f2bf(f.y);
        Ws[(n4 + 2) * 72 + k] = f2bf(f.z);
        Ws[(n4 + 3) * 72 + k] = f2bf(f.w);
    }
    __syncthreads();
    for (int i = tid; i < 512; i += 256) {        // 8 frags x 64 n
        const int p = i >> 6, n = i & 63;
        const uint4 v = *(const uint4*)&Ws[n * 72 + p * 8];
        *(uint4*)(Wt_g + ((size_t)y << 16) + (size_t)(((win * 8 + p) * 64 + n) * 8)) = v;
    }
}

// ---------------------------------------------------------------------------
// Projection: out[M,64] = bf16(X @ W + b). grid (256 row-tiles, 3), block 256.
// X (the 201MB stream) DMA'd via global_load_lds into a double-buffered
// 2x16KB fp32 LDS tile (XOR-swizzled), SINGLE barrier per 64-k window with
// DMA issued AFTER the barrier -> each DMA has a full iteration of cover and
// in-flight bytes live in LDS, not VGPRs. W: 2-deep register pipeline from
// the fragment-major bf16 image (coalesced, L1-resident). Q pre-scaled by
// 0.125*log2e. V written transposed Vt[b][d][s]; transpose LDS aliases Xs.
// ---------------------------------------------------------------------------
__global__ __launch_bounds__(256, 3) void proj_kernel(
    const float* __restrict__ Xq, const float* __restrict__ Xk, const float* __restrict__ Xv,
    const float* __restrict__ bq, const float* __restrict__ bk, const float* __restrict__ bv,
    const ushort* __restrict__ Wt_g,
    ushort* __restrict__ Qb, ushort* __restrict__ Kb, ushort* __restrict__ Vt)
{
    const int y = blockIdx.y;
    const float *X, *bias;
    if (y == 0)      { X = Xq; bias = bq; }
    else if (y == 1) { X = Xk; bias = bk; }
    else             { X = Xv; bias = bv; }

    __shared__ float Xs[2][4096];    // 2 x 16KB: [row(64)][chunk p(16)][4 fp32]

    const int tid  = threadIdx.x;
    const int w    = tid >> 6;
    const int lane = tid & 63;
    const int m    = lane & 15;
    const int quad = lane >> 4;
    const int row0 = blockIdx.x * 64;

    const ushort* wbase = Wt_g + ((size_t)y << 16);

    float bias_v[4];
    #pragma unroll
    for (int nt = 0; nt < 4; ++nt) bias_v[nt] = bias[nt * 16 + m];

    // per-lane DMA source precompute: wave w, slice i covers rows (w*4+i)*4..+3
    // g = (w*4+i)*64 + lane ; row = g>>4 ; phys chunk p = lane&15 ;
    // logical chunk c = xswz(p,row) (involution) ; src k-offset = c*4
    int dma_row[4], dma_koff[4];
    #pragma unroll
    for (int i = 0; i < 4; ++i) {
        const int g = (w * 4 + i) * 64 + lane;
        dma_row[i]  = g >> 4;
        dma_koff[i] = xswz(g & 15, g >> 4) * 4;
    }

    #define ISSUE_X(IT, NB)                                                         \
        do {                                                                        \
            _Pragma("unroll")                                                       \
            for (int i = 0; i < 4; ++i)                                             \
                __builtin_amdgcn_global_load_lds(                                   \
                    GPTR(X + (size_t)(row0 + dma_row[i]) * DIN + (IT) * 64          \
                         + dma_koff[i]),                                            \
                    LPTR(&Xs[NB][(w * 4 + i) * 256]), 16, 0, 0);                    \
        } while (0)

    f32x4 acc[4] = {};
    bf16x8 wcur[8], wnxt[8];

    // prologue: DMA window 0, W frags window 0
    ISSUE_X(0, 0);
    #pragma unroll
    for (int ks = 0; ks < 2; ++ks)
        #pragma unroll
        for (int nt = 0; nt < 4; ++nt)
            wcur[ks * 4 + nt] = *(const bf16x8*)(wbase
                + (size_t)(((ks * 4 + quad) * 64 + nt * 16 + m) * 8));

    const int r = w * 16 + m;                  // this lane's A-row
    for (int it = 0; it < 16; ++it) {
        __syncthreads();                       // drains DMA(it), issued 1 iter ago
        if (it < 15) {
            ISSUE_X(it + 1, (it + 1) & 1);
            #pragma unroll
            for (int ks = 0; ks < 2; ++ks)
                #pragma unroll
                for (int nt = 0; nt < 4; ++nt)
                    wnxt[ks * 4 + nt] = *(const bf16x8*)(wbase
                        + (size_t)((((it + 1) * 8 + ks * 4 + quad) * 64 + nt * 16 + m) * 8));
        }
        const float* buf = Xs[it & 1];
        #pragma unroll
        for (int ks = 0; ks < 2; ++ks) {
            const int c0 = ks * 8 + quad * 2;
            const float4 xa = *(const float4*)&buf[r * 64 + xswz(c0, m) * 4];
            const float4 xb = *(const float4*)&buf[r * 64 + xswz(c0 + 1, m) * 4];
            const bf16x8 a = cvt8(xa, xb);
            #pragma unroll
            for (int nt = 0; nt < 4; ++nt)
                acc[nt] = __builtin_amdgcn_mfma_f32_16x16x32_bf16(
                    a, wcur[ks * 4 + nt], acc[nt], 0, 0, 0);
        }
        #pragma unroll
        for (int i = 0; i < 8; ++i) wcur[i] = wnxt[i];
    }

    if (y < 2) {
        ushort* Out = (y == 0) ? Qb : Kb;
        const float sc = (y == 0) ? QSCALE : 1.0f;
        #pragma unroll
        for (int nt = 0; nt < 4; ++nt)
            #pragma unroll
            for (int j = 0; j < 4; ++j) {
                const int row = row0 + w * 16 + quad * 4 + j;
                Out[(size_t)row * DH + nt * 16 + m] = f2bf((acc[nt][j] + bias_v[nt]) * sc);
            }
    } else {
        // V transpose via LDS aliasing Xs (all waves past final barrier's reads)
        __syncthreads();
        ushort* Vx = (ushort*)&Xs[0][0];       // pitch 72, chunk-XOR swizzled
        #pragma unroll
        for (int nt = 0; nt < 4; ++nt)
            #pragma unroll
            for (int j = 0; j < 4; ++j) {
                const int d = nt * 16 + m;
                const int s = w * 16 + quad * 4 + j;
                Vx[d * 72 + (((s >> 3) ^ (d & 7)) * 8) + (s & 7)] = f2bf(acc[nt][j] + bias_v[nt]);
            }
        __syncthreads();
        const int batch = row0 >> 12;
        const int s0    = row0 & 4095;
        for (int i = tid; i < 512; i += 256) {
            const int d = i >> 3, c = i & 7;
            const uint4 v = *(const uint4*)&Vx[d * 72 + ((c ^ (d & 7)) * 8)];
            *(uint4*)(Vt + ((size_t)batch * 64 + d) * S_ + s0 + c * 8) = v;
        }
    }
    #undef ISSUE_X
}

// ---------------------------------------------------------------------------
// Flash attention (unchanged from R5): bf16 MFMA, no online max, exp2
// softmax, single-barrier double-buffered K/V DMA, XOR source swizzle,
// per-wave P stripe. grid (64,4,4) = 1024 blocks.
// ---------------------------------------------------------------------------
__global__ __launch_bounds__(256, 3) void attn_kernel(
    const ushort* __restrict__ Qb, const ushort* __restrict__ Kb,
    const ushort* __restrict__ Vt, float* __restrict__ Opart, float* __restrict__ Lpart)
{
    __shared__ ushort Ks[2][4096];
    __shared__ ushort Vs[2][4096];
    __shared__ ushort Pt[64 * 72];

    const int tid  = threadIdx.x;
    const int w    = tid >> 6;
    const int lane = tid & 63;
    const int m    = lane & 15;
    const int quad = lane >> 4;
    const int b    = blockIdx.z, jc = blockIdx.y, qt = blockIdx.x;
    const int q0   = qt * 64;

    bf16x8 qf[2];
    #pragma unroll
    for (int ks = 0; ks < 2; ++ks)
        qf[ks] = *(const bf16x8*)(Qb + (size_t)(b * S_ + q0 + w * 16 + m) * 64
                                     + ks * 32 + quad * 8);

    f32x4 acc_o[4] = {};
    float Lp[4] = {};

    const ushort* kbase = Kb + (size_t)b * S_ * 64;
    const ushort* vbase = Vt + (size_t)b * 64 * S_;

    const int slot0 = w * 128 + lane;
    const int j0 = slot0 >> 3, c0 = slot0 & 7;
    const int j1 = (slot0 + 64) >> 3, c1 = (slot0 + 64) & 7;

    #define ISSUE_DMA(IT, NB)                                                          \
        do {                                                                           \
            const int _jt = jc * 16 + (IT);                                            \
            __builtin_amdgcn_global_load_lds(                                          \
                GPTR(kbase + (size_t)(_jt * 64 + j0) * 64 + ((c0 ^ (j0 & 7)) * 8)),    \
                LPTR(&Ks[NB][(w * 128) * 8]), 16, 0, 0);                               \
            __builtin_amdgcn_global_load_lds(                                          \
                GPTR(kbase + (size_t)(_jt * 64 + j1) * 64 + ((c1 ^ (j1 & 7)) * 8)),    \
                LPTR(&Ks[NB][(w * 128 + 64) * 8]), 16, 0, 0);                          \
            __builtin_amdgcn_global_load_lds(                                          \
                GPTR(vbase + (size_t)j0 * S_ + _jt * 64 + ((c0 ^ (j0 & 7)) * 8)),      \
                LPTR(&Vs[NB][(w * 128) * 8]), 16, 0, 0);                               \
            __builtin_amdgcn_global_load_lds(                                          \
                GPTR(vbase + (size_t)j1 * S_ + _jt * 64 + ((c1 ^ (j1 & 7)) * 8)),      \
                LPTR(&Vs[NB][(w * 128 + 64) * 8]), 16, 0, 0);                          \
        } while (0)

    ISSUE_DMA(0, 0);

    for (int it = 0; it < 16; ++it) {
        __syncthreads();
        if (it < 15) ISSUE_DMA(it + 1, (it + 1) & 1);
        const int cb = it & 1;

        f32x4 acc_s[4] = {};
        #pragma unroll
        for (int ks = 0; ks < 2; ++ks)
            #pragma unroll
            for (int jt4 = 0; jt4 < 4; ++jt4) {
                const int j = jt4 * 16 + m;
                const bf16x8 kf = *(const bf16x8*)&Ks[cb][j * 64 + (((ks * 4 + quad) ^ (j & 7)) * 8)];
                acc_s[jt4] = __builtin_amdgcn_mfma_f32_16x16x32_bf16(
                    qf[ks], kf, acc_s[jt4], 0, 0, 0);
            }

        #pragma unroll
        for (int jt4 = 0; jt4 < 4; ++jt4)
            #pragma unroll
            for (int r = 0; r < 4; ++r) {
                const float e = exp2f(acc_s[jt4][r]);
                Lp[r] += e;
                Pt[(w * 16 + quad * 4 + r) * 72 + jt4 * 16 + m] = f2bf(e);
            }

        #pragma unroll
        for (int jc2 = 0; jc2 < 2; ++jc2) {
            const bf16x8 pf = *(const bf16x8*)&Pt[(w * 16 + m) * 72 + jc2 * 32 + quad * 8];
            #pragma unroll
            for (int dt = 0; dt < 4; ++dt) {
                const int d = dt * 16 + m;
                const bf16x8 vf = *(const bf16x8*)&Vs[cb][d * 64 + (((jc2 * 4 + quad) ^ (d & 7)) * 8)];
                acc_o[dt] = __builtin_amdgcn_mfma_f32_16x16x32_bf16(pf, vf, acc_o[dt], 0, 0, 0);
            }
        }
    }
    #undef ISSUE_DMA

    #pragma unroll
    for (int r = 0; r < 4; ++r) {
        float s = Lp[r];
        #pragma unroll
        for (int off = 1; off < 16; off <<= 1)
            s += __shfl_xor(s, off, 64);
        Lp[r] = s;
    }

    const size_t bj = (size_t)(b * 4 + jc);
    float* Ob = Opart + (bj << 18);
    #pragma unroll
    for (int dt = 0; dt < 4; ++dt)
        #pragma unroll
        for (int r = 0; r < 4; ++r) {
            const int row = q0 + w * 16 + quad * 4 + r;
            Ob[(size_t)row * 64 + dt * 16 + m] = acc_o[dt][r];
        }
    if (m == 0) {
        #pragma unroll
        for (int r = 0; r < 4; ++r)
            Lpart[bj * 4096 + q0 + w * 16 + quad * 4 + r] = Lp[r];
    }
}

// ---------------------------------------------------------------------------
// Combine j-chunk partials: out = (sum_jc O) / (sum_jc L)
// ---------------------------------------------------------------------------
__global__ __launch_bounds__(256) void reduce_kernel(
    const float* __restrict__ Opart, const float* __restrict__ Lpart, float* __restrict__ out)
{
    const int g    = blockIdx.x * 256 + threadIdx.x;
    const int base = g << 2;
    const int b    = base >> 18;
    const int rem  = base & 0x3FFFF;
    const int q    = rem >> 6;
    float4 o = make_float4(0.f, 0.f, 0.f, 0.f);
    float  l = 0.f;
    #pragma unroll
    for (int jcc = 0; jcc < 4; ++jcc) {
        const float4 p = *(const float4*)(Opart + (((size_t)(b * 4 + jcc)) << 18) + rem);
        o.x += p.x; o.y += p.y; o.z += p.z; o.w += p.w;
        l += Lpart[(size_t)(b * 4 + jcc) * 4096 + q];
    }
    const float inv = 1.0f / l;
    o.x *= inv; o.y *= inv; o.z *= inv; o.w *= inv;
    *(float4*)(out + base) = o;
}

// ---------------------------------------------------------------------------
extern "C" void kernel_launch(void* const* d_in, const int* in_sizes, int n_in,
                              void* d_out, int out_size, void* d_ws, size_t ws_size,
                              hipStream_t stream)
{
    const float* query = (const float*)d_in[0];
    const float* key_  = (const float*)d_in[1];
    const float* value = (const float*)d_in[2];
    const float* Wq    = (const float*)d_in[3];
    const float* bq    = (const float*)d_in[4];
    const float* Wk    = (const float*)d_in[5];
    const float* bk    = (const float*)d_in[6];
    const float* Wv    = (const float*)d_in[7];
    const float* bv    = (const float*)d_in[8];
    float* out = (float*)d_out;

    // ws: Qb 2MB | Kb 2MB | Vt 2MB | Opart 16MB | Lpart 256KB  (22.25MB)
    // Wt_g (384KB) ALIASES Opart: consumed by proj before attn writes Opart.
    char* ws = (char*)d_ws;
    ushort* Qb    = (ushort*)(ws);
    ushort* Kb    = (ushort*)(ws + (2  << 20));
    ushort* Vt    = (ushort*)(ws + (4  << 20));
    float*  Opart = (float*) (ws + (6  << 20));
    float*  Lpart = (float*) (ws + (22 << 20));
    ushort* Wt_g  = (ushort*)(ws + (6  << 20));

    setup_w<<<dim3(16, 3), 256, 0, stream>>>(Wq, Wk, Wv, Wt_g);
    proj_kernel<<<dim3(256, 3), 256, 0, stream>>>(
        query, key_, value, bq, bk, bv, Wt_g, Qb, Kb, Vt);
    attn_kernel<<<dim3(64, 4, 4), 256, 0, stream>>>(Qb, Kb, Vt, Opart, Lpart);
    reduce_kernel<<<dim3(1024), 256, 0, stream>>>(Opart, Lpart, out);
}